// Round 3
// baseline (435.411 us; speedup 1.0000x reference)
//
#include <hip/hip_runtime.h>
#include <hip/hip_bf16.h>
#include <math.h>

#define N_NODES 100000
#define N_EDGES 1600000
#define D_IN    256
#define D_HID   64
#define N_CLASS 40

#define SCAN_CHUNK 256
#define SCAN_NB    ((N_NODES + SCAN_CHUNK - 1) / SCAN_CHUNK)   // 391
#define SLOT_MAX   48     // Binomial(1.6M,1e-5): mean 16, P(deg>48) ~ 1e-10
#define GEMM_NB    ((N_NODES + 255) / 256)                     // 391
#define FILL_NB    1024                                        // persistent fill blocks
#define EDGE_NB    ((N_EDGES + 255) / 256)                     // 6250 (fallback hist/fill)
#define NPASS      8                                           // dst-range passes
#define PASS_RNG   ((N_NODES + NPASS - 1) / NPASS)             // 12500 -> 4.8MB slots/pass

// ---------------------------------------------------------------------------
// prep: W12t[c][k] = sum_j W1[k][j]*W2[j][c]  (transposed 40x256),
//       c1[c] = sum_j b1[j]*W2[j][c]
// ---------------------------------------------------------------------------
__global__ __launch_bounds__(256) void prep_kernel(
    const float* __restrict__ W1, const float* __restrict__ W2,
    const float* __restrict__ b1, float* __restrict__ W12t, float* __restrict__ c1)
{
    int idx = blockIdx.x * 256 + threadIdx.x;
    if (idx < D_IN * N_CLASS) {
        int k = idx / N_CLASS;
        int c = idx - k * N_CLASS;
        float s = 0.f;
#pragma unroll
        for (int j = 0; j < D_HID; ++j)
            s = fmaf(W1[k * D_HID + j], W2[j * N_CLASS + c], s);
        W12t[c * D_IN + k] = s;
    }
    if (blockIdx.x == 0 && threadIdx.x < N_CLASS) {
        int c = threadIdx.x;
        float s = 0.f;
#pragma unroll
        for (int j = 0; j < D_HID; ++j)
            s = fmaf(b1[j], W2[j * N_CLASS + c], s);
        c1[c] = s;
    }
}

// ---------------------------------------------------------------------------
// gemm body (round-0 v3, verified): 256 rows x 40 cols per block, both
// operands in LDS, XOR-swizzled X tile, thread = 4 rows x 10 cols.
// 16 distinct LDS addresses per wave-read (4-lane broadcast) -> <=2 addr/bank
// -> 0 bank conflicts (measured). All-LDS inner loop keeps lgkmcnt
// fine-grained (no SMEM mixing).
// ---------------------------------------------------------------------------
__device__ __forceinline__ void gemm_body(
    int gblk, int tid,
    const float* __restrict__ x, const float* __restrict__ W12t,
    float* __restrict__ T, float* xs, float* wt)
{
    const int row0 = gblk * 256;

    for (int i = tid; i < N_CLASS * D_IN; i += 256) {
        int c = i >> 8;
        int k = i & 255;
        wt[c * 260 + k] = W12t[i];
    }

    const int rg = tid >> 2;       // 0..63  (4 rows each)
    const int cg = tid & 3;        // 0..3   (10 cols each)
    const int c0 = cg * 10;

    float acc[4][10];
#pragma unroll
    for (int r = 0; r < 4; ++r)
#pragma unroll
        for (int j = 0; j < 10; ++j) acc[r][j] = 0.f;

    const float4* x4 = (const float4*)x;
    float4* xs4 = (float4*)xs;
    const float4* wt4 = (const float4*)wt;

    for (int kb = 0; kb < 8; ++kb) {
        __syncthreads();
#pragma unroll
        for (int ph = 0; ph < 8; ++ph) {
            int i = ph * 256 + tid;
            int r  = i >> 3;
            int c4 = i & 7;
            int grow = min(row0 + r, N_NODES - 1);
            float4 v = x4[(size_t)grow * 64 + kb * 8 + c4];
            xs4[r * 8 + (c4 ^ ((r >> 2) & 7))] = v;
        }
        __syncthreads();

#pragma unroll
        for (int k4 = 0; k4 < 8; ++k4) {
            float4 xv[4];
#pragma unroll
            for (int r = 0; r < 4; ++r)
                xv[r] = xs4[(rg * 4 + r) * 8 + (k4 ^ (rg & 7))];
#pragma unroll
            for (int j = 0; j < 10; ++j) {
                float4 w = wt4[(c0 + j) * 65 + kb * 8 + k4];
#pragma unroll
                for (int r = 0; r < 4; ++r)
                    acc[r][j] = fmaf(xv[r].x, w.x,
                                fmaf(xv[r].y, w.y,
                                fmaf(xv[r].z, w.z,
                                fmaf(xv[r].w, w.w, acc[r][j]))));
            }
        }
    }

#pragma unroll
    for (int r = 0; r < 4; ++r) {
        int row = row0 + rg * 4 + r;
        if (row < N_NODES) {
            size_t ob = (size_t)row * N_CLASS + c0;
#pragma unroll
            for (int j = 0; j < 10; ++j) T[ob + j] = acc[r][j];
        }
    }
}

// ---------------------------------------------------------------------------
// fused gemm + fill_slots. Blocks [0,GEMM_NB): dense transform (round-0
// body). Blocks [GEMM_NB, GEMM_NB+FILL_NB): slot-binning in NPASS dst-range
// passes so the live scatter region per pass is 4.8MB (L2-coalescible) —
// a node's ~16 slot writes merge in L2 before writeback instead of each
// RFO-ing its 64B line from HBM. edst/esrc/ew re-reads hit L3.
// Passes are independent (each edge belongs to exactly one pass) -> no sync.
// ---------------------------------------------------------------------------
__global__ __launch_bounds__(256) void gemm_fill_kernel(
    const float* __restrict__ x, const float* __restrict__ W12t,
    float* __restrict__ T,
    const int* __restrict__ esrc, const int* __restrict__ edst,
    const float* __restrict__ ew, int* __restrict__ cnt,
    int2* __restrict__ slots)
{
    __shared__ float xs[256 * 32];      // 32 KB
    __shared__ float wt[N_CLASS * 260]; // 41.6 KB  (74.4 KB -> 2 blocks/CU)
    const int tid = threadIdx.x;

    if (blockIdx.x < GEMM_NB) {
        gemm_body(blockIdx.x, tid, x, W12t, T, xs, wt);
    } else {
        const int b = blockIdx.x - GEMM_NB;
        for (int p = 0; p < NPASS; ++p) {
            const int dlo = p * PASS_RNG;
            const int dhi = dlo + PASS_RNG;
            for (int e = b * 256 + tid; e < N_EDGES; e += FILL_NB * 256) {
                int d = edst[e];
                if (d >= dlo && d < dhi) {
                    int slot = atomicAdd(&cnt[d], 1);
                    if (slot < SLOT_MAX)
                        slots[(size_t)d * SLOT_MAX + slot] =
                            make_int2(esrc[e], __float_as_int(ew[e]));
                }
            }
        }
    }
}

// standalone gemm (CSR fallback path)
__global__ __launch_bounds__(256) void gemm_t_kernel(
    const float* __restrict__ x, const float* __restrict__ W12t,
    float* __restrict__ T)
{
    __shared__ float xs[256 * 32];
    __shared__ float wt[N_CLASS * 260];
    gemm_body(blockIdx.x, threadIdx.x, x, W12t, T, xs, wt);
}

// ---------------------------------------------------------------------------
// CSR fallback: hist + 3-phase scan + fill
// ---------------------------------------------------------------------------
__global__ __launch_bounds__(256) void hist_kernel(
    const int* __restrict__ edst, int* __restrict__ cnt)
{
    int e = blockIdx.x * 256 + threadIdx.x;
    if (e >= N_EDGES) return;
    atomicAdd(&cnt[edst[e]], 1);
}

__global__ __launch_bounds__(256) void scan_partial_kernel(
    const int* __restrict__ cnt, int* __restrict__ bsum)
{
    __shared__ int red[256];
    int t = threadIdx.x;
    int idx = blockIdx.x * SCAN_CHUNK + t;
    int v = (idx < N_NODES) ? cnt[idx] : 0;
    red[t] = v;
    __syncthreads();
#pragma unroll
    for (int off = 128; off > 0; off >>= 1) {
        if (t < off) red[t] += red[t + off];
        __syncthreads();
    }
    if (t == 0) bsum[blockIdx.x] = red[0];
}

__global__ __launch_bounds__(512) void scan_block_kernel(
    const int* __restrict__ bsum, int* __restrict__ boff)
{
    __shared__ int s[512];
    int t = threadIdx.x;
    int v = (t < SCAN_NB) ? bsum[t] : 0;
    s[t] = v;
    __syncthreads();
#pragma unroll
    for (int off = 1; off < 512; off <<= 1) {
        int u = (t >= off) ? s[t - off] : 0;
        __syncthreads();
        s[t] += u;
        __syncthreads();
    }
    if (t < SCAN_NB) boff[t] = s[t] - v;
}

__global__ __launch_bounds__(256) void scan_final_kernel(
    const int* __restrict__ cnt, const int* __restrict__ boff,
    int* __restrict__ row_ptr)
{
    __shared__ int s[256];
    int t = threadIdx.x;
    int idx = blockIdx.x * SCAN_CHUNK + t;
    int v = (idx < N_NODES) ? cnt[idx] : 0;
    s[t] = v;
    __syncthreads();
#pragma unroll
    for (int off = 1; off < 256; off <<= 1) {
        int u = (t >= off) ? s[t - off] : 0;
        __syncthreads();
        s[t] += u;
        __syncthreads();
    }
    if (idx < N_NODES) row_ptr[idx] = boff[blockIdx.x] + s[t] - v;
}

__global__ __launch_bounds__(256) void fill_kernel(
    const int* __restrict__ esrc, const int* __restrict__ edst,
    const float* __restrict__ ew, int* __restrict__ row_ptr,
    int2* __restrict__ edges_s)
{
    int e = blockIdx.x * 256 + threadIdx.x;
    if (e >= N_EDGES) return;
    int d = edst[e];
    int pos = atomicAdd(&row_ptr[d], 1);
    edges_s[pos] = make_int2(esrc[e], __float_as_int(ew[e]));
}

// ---------------------------------------------------------------------------
// agg: Tout[d,:] = sum_e w_e * Tin[src_e,:].  10 lanes x float4 per node,
// 25 nodes / 256-block. 8-wide edge unroll (was 4): 8 independent gather
// chains in flight per lane -> 2x MLP for the L2-latency-bound gather.
// SMAX: fused bias + deg_w*c1 + log_softmax epilogue.
// ---------------------------------------------------------------------------
template<bool SLOTS, bool SMAX>
__global__ __launch_bounds__(256) void agg_kernel(
    const int2* __restrict__ edges_s, const int* __restrict__ meta,
    const float* __restrict__ Tin, float* __restrict__ Tout,
    const float* __restrict__ c1, const float* __restrict__ b2)
{
    __shared__ float red[25][11];
    __shared__ float wsh[25];
    const int t = threadIdx.x;
    const int nl  = t / 10;                 // 0..25 (idle if >=25)
    const int sub = t % 10;
    const int node = blockIdx.x * 25 + nl;
    const bool active = (t < 250) && (node < N_NODES);

    int beg = 0, end = 0;
    if (active) {
        if (SLOTS) {
            beg = node * SLOT_MAX;
            int c = meta[node];
            end = beg + (c > SLOT_MAX ? SLOT_MAX : c);
        } else {
            beg = node ? meta[node - 1] : 0;
            end = meta[node];
        }
    }

    const float4* Tin4 = (const float4*)Tin;
    float4 acc = make_float4(0.f, 0.f, 0.f, 0.f);
    float wsum = 0.f;

    int e = beg;
    for (; e + 7 < end; e += 8) {
        int2 a[8];
        float4 v[8];
#pragma unroll
        for (int q = 0; q < 8; ++q) a[q] = edges_s[e + q];
#pragma unroll
        for (int q = 0; q < 8; ++q) v[q] = Tin4[a[q].x * 10 + sub];
#pragma unroll
        for (int q = 0; q < 8; ++q) {
            float w = __int_as_float(a[q].y);
            acc.x = fmaf(w, v[q].x, acc.x);
            acc.y = fmaf(w, v[q].y, acc.y);
            acc.z = fmaf(w, v[q].z, acc.z);
            acc.w = fmaf(w, v[q].w, acc.w);
            if (SMAX) wsum += w;
        }
    }
    for (; e + 3 < end; e += 4) {
        int2 a[4];
        float4 v[4];
#pragma unroll
        for (int q = 0; q < 4; ++q) a[q] = edges_s[e + q];
#pragma unroll
        for (int q = 0; q < 4; ++q) v[q] = Tin4[a[q].x * 10 + sub];
#pragma unroll
        for (int q = 0; q < 4; ++q) {
            float w = __int_as_float(a[q].y);
            acc.x = fmaf(w, v[q].x, acc.x);
            acc.y = fmaf(w, v[q].y, acc.y);
            acc.z = fmaf(w, v[q].z, acc.z);
            acc.w = fmaf(w, v[q].w, acc.w);
            if (SMAX) wsum += w;
        }
    }
    for (; e < end; ++e) {
        int2 a0 = edges_s[e];
        float w0 = __int_as_float(a0.y);
        float4 v0 = Tin4[a0.x * 10 + sub];
        acc.x = fmaf(w0, v0.x, acc.x);
        acc.y = fmaf(w0, v0.y, acc.y);
        acc.z = fmaf(w0, v0.z, acc.z);
        acc.w = fmaf(w0, v0.w, acc.w);
        if (SMAX) wsum += w0;
    }

    if (!SMAX) {
        if (active) ((float4*)Tout)[(size_t)node * 10 + sub] = acc;
        return;
    }

    // ---- fused bias + log_softmax epilogue (all 256 threads hit syncs) ----
    if (active && sub == 0) wsh[nl] = wsum;
    __syncthreads();
    float dw = active ? wsh[nl] : 0.f;

    float4 cv = ((const float4*)c1)[sub];
    float4 bv = ((const float4*)b2)[sub];
    float4 z;
    z.x = fmaf(dw, cv.x, acc.x + bv.x);
    z.y = fmaf(dw, cv.y, acc.y + bv.y);
    z.z = fmaf(dw, cv.z, acc.z + bv.z);
    z.w = fmaf(dw, cv.w, acc.w + bv.w);

    float m4 = fmaxf(fmaxf(z.x, z.y), fmaxf(z.z, z.w));
    if (active) red[nl][sub] = m4;
    __syncthreads();
    float m = -INFINITY;
    if (active)
#pragma unroll
        for (int j = 0; j < 10; ++j) m = fmaxf(m, red[nl][j]);
    __syncthreads();

    float s4 = expf(z.x - m) + expf(z.y - m) + expf(z.z - m) + expf(z.w - m);
    if (active) red[nl][sub] = s4;
    __syncthreads();
    if (active) {
        float s = 0.f;
#pragma unroll
        for (int j = 0; j < 10; ++j) s += red[nl][j];
        float ls = m + logf(s);
        float4 o;
        o.x = z.x - ls; o.y = z.y - ls; o.z = z.z - ls; o.w = z.w - ls;
        ((float4*)Tout)[(size_t)node * 10 + sub] = o;
    }
}

// ---------------------------------------------------------------------------
extern "C" void kernel_launch(void* const* d_in, const int* in_sizes, int n_in,
                              void* d_out, int out_size, void* d_ws, size_t ws_size,
                              hipStream_t stream)
{
    const float* x    = (const float*)d_in[0];
    const int*   esrc = (const int*)  d_in[1];
    const int*   edst = (const int*)  d_in[2];
    const float* ew   = (const float*)d_in[3];
    const float* W1   = (const float*)d_in[4];
    const float* b1   = (const float*)d_in[5];
    const float* W2   = (const float*)d_in[6];
    const float* b2   = (const float*)d_in[7];
    float* out = (float*)d_out;

    char* ws = (char*)d_ws;
    const size_t SLOTS_BYTES = (size_t)N_NODES * SLOT_MAX * 8;     // 38.4 MB
    const size_t NEED_SLOTS  = SLOTS_BYTES + 32000000 + 1000000;   // ~71.4 MB
    const bool use_slots = (ws_size >= NEED_SLOTS);

    if (use_slots) {
        int2*  slots = (int2*) (ws);
        float* T     = (float*)(ws + SLOTS_BYTES);                  // 16 MB
        float* Y1    = (float*)(ws + SLOTS_BYTES + 16000000);       // 16 MB
        int*   cnt   = (int*)  (ws + SLOTS_BYTES + 32000000);       // 400 KB
        float* W12t  = (float*)(ws + SLOTS_BYTES + 32400000);       // 40 KB
        float* c1    = (float*)(ws + SLOTS_BYTES + 32441984);

        hipMemsetAsync(cnt, 0, 400000, stream);
        prep_kernel<<<(D_IN * N_CLASS + 255) / 256, 256, 0, stream>>>(W1, W2, b1, W12t, c1);
        gemm_fill_kernel<<<GEMM_NB + FILL_NB, 256, 0, stream>>>(
            x, W12t, T, esrc, edst, ew, cnt, slots);
        agg_kernel<true, false><<<(N_NODES + 24) / 25, 256, 0, stream>>>(
            slots, cnt, T, Y1, nullptr, nullptr);
        agg_kernel<true, true><<<(N_NODES + 24) / 25, 256, 0, stream>>>(
            slots, cnt, Y1, out, c1, b2);
    } else {
        float* T       = (float*)(ws);                         // 16 MB
        float* Y1      = (float*)(ws + 16000000);              // 16 MB
        int2*  edges_s = (int2*) (ws + 32000000);              // 12.8 MB
        int*   row_ptr = (int*)  (ws + 44800000);              // 400 KB
        int*   cnt     = (int*)  (ws + 45200016);              // 400 KB
        float* W12t    = (float*)(ws + 45600016);              // 40 KB
        float* c1      = (float*)(ws + 45640976);
        int*   bsum    = (int*)  (ws + 45641200);
        int*   boff    = (int*)  (ws + 45642800);

        hipMemsetAsync(cnt, 0, 400000, stream);
        prep_kernel<<<(D_IN * N_CLASS + 255) / 256, 256, 0, stream>>>(W1, W2, b1, W12t, c1);
        gemm_t_kernel<<<GEMM_NB, 256, 0, stream>>>(x, W12t, T);
        hist_kernel<<<EDGE_NB, 256, 0, stream>>>(edst, cnt);
        scan_partial_kernel<<<SCAN_NB, 256, 0, stream>>>(cnt, bsum);
        scan_block_kernel<<<1, 512, 0, stream>>>(bsum, boff);
        scan_final_kernel<<<SCAN_NB, 256, 0, stream>>>(cnt, boff, row_ptr);
        fill_kernel<<<EDGE_NB, 256, 0, stream>>>(esrc, edst, ew, row_ptr, edges_s);
        agg_kernel<false, false><<<(N_NODES + 24) / 25, 256, 0, stream>>>(
            edges_s, row_ptr, T, Y1, nullptr, nullptr);
        agg_kernel<false, true><<<(N_NODES + 24) / 25, 256, 0, stream>>>(
            edges_s, row_ptr, Y1, out, c1, b2);
    }
}

// Round 4
// 414.153 us; speedup vs baseline: 1.0513x; 1.0513x over previous
//
#include <hip/hip_runtime.h>
#include <hip/hip_bf16.h>
#include <math.h>

#define N_NODES 100000
#define N_EDGES 1600000
#define D_IN    256
#define D_HID   64
#define N_CLASS 40

#define SCAN_CHUNK 256
#define SCAN_NB    ((N_NODES + SCAN_CHUNK - 1) / SCAN_CHUNK)   // 391
#define SLOT_MAX   48     // Binomial(1.6M,1e-5): mean 16, P(deg>48) ~ 1e-10
#define GEMM_NB    ((N_NODES + 255) / 256)                     // 391
#define EDGE_NB    ((N_EDGES + 255) / 256)                     // 6250

// ---------------------------------------------------------------------------
// prep: W12t[c][k] = sum_j W1[k][j]*W2[j][c]  (transposed 40x256),
//       c1[c] = sum_j b1[j]*W2[j][c]
// ---------------------------------------------------------------------------
__global__ __launch_bounds__(256) void prep_kernel(
    const float* __restrict__ W1, const float* __restrict__ W2,
    const float* __restrict__ b1, float* __restrict__ W12t, float* __restrict__ c1)
{
    int idx = blockIdx.x * 256 + threadIdx.x;
    if (idx < D_IN * N_CLASS) {
        int k = idx / N_CLASS;
        int c = idx - k * N_CLASS;
        float s = 0.f;
#pragma unroll
        for (int j = 0; j < D_HID; ++j)
            s = fmaf(W1[k * D_HID + j], W2[j * N_CLASS + c], s);
        W12t[c * D_IN + k] = s;
    }
    if (blockIdx.x == 0 && threadIdx.x < N_CLASS) {
        int c = threadIdx.x;
        float s = 0.f;
#pragma unroll
        for (int j = 0; j < D_HID; ++j)
            s = fmaf(b1[j], W2[j * N_CLASS + c], s);
        c1[c] = s;
    }
}

// ---------------------------------------------------------------------------
// gemm body (round-0 v3, verified): 256 rows x 40 cols per block, both
// operands in LDS, XOR-swizzled X tile, thread = 4 rows x 10 cols.
// 16 distinct LDS addresses per wave-read (4-lane broadcast) -> <=2 addr/bank
// -> 0 bank conflicts (measured).
// ---------------------------------------------------------------------------
__device__ __forceinline__ void gemm_body(
    int gblk, int tid,
    const float* __restrict__ x, const float* __restrict__ W12t,
    float* __restrict__ T, float* xs, float* wt)
{
    const int row0 = gblk * 256;

    for (int i = tid; i < N_CLASS * D_IN; i += 256) {
        int c = i >> 8;
        int k = i & 255;
        wt[c * 260 + k] = W12t[i];
    }

    const int rg = tid >> 2;       // 0..63  (4 rows each)
    const int cg = tid & 3;        // 0..3   (10 cols each)
    const int c0 = cg * 10;

    float acc[4][10];
#pragma unroll
    for (int r = 0; r < 4; ++r)
#pragma unroll
        for (int j = 0; j < 10; ++j) acc[r][j] = 0.f;

    const float4* x4 = (const float4*)x;
    float4* xs4 = (float4*)xs;
    const float4* wt4 = (const float4*)wt;

    for (int kb = 0; kb < 8; ++kb) {
        __syncthreads();
#pragma unroll
        for (int ph = 0; ph < 8; ++ph) {
            int i = ph * 256 + tid;
            int r  = i >> 3;
            int c4 = i & 7;
            int grow = min(row0 + r, N_NODES - 1);
            float4 v = x4[(size_t)grow * 64 + kb * 8 + c4];
            xs4[r * 8 + (c4 ^ ((r >> 2) & 7))] = v;
        }
        __syncthreads();

#pragma unroll
        for (int k4 = 0; k4 < 8; ++k4) {
            float4 xv[4];
#pragma unroll
            for (int r = 0; r < 4; ++r)
                xv[r] = xs4[(rg * 4 + r) * 8 + (k4 ^ (rg & 7))];
#pragma unroll
            for (int j = 0; j < 10; ++j) {
                float4 w = wt4[(c0 + j) * 65 + kb * 8 + k4];
#pragma unroll
                for (int r = 0; r < 4; ++r)
                    acc[r][j] = fmaf(xv[r].x, w.x,
                                fmaf(xv[r].y, w.y,
                                fmaf(xv[r].z, w.z,
                                fmaf(xv[r].w, w.w, acc[r][j]))));
            }
        }
    }

#pragma unroll
    for (int r = 0; r < 4; ++r) {
        int row = row0 + rg * 4 + r;
        if (row < N_NODES) {
            size_t ob = (size_t)row * N_CLASS + c0;
#pragma unroll
            for (int j = 0; j < 10; ++j) T[ob + j] = acc[r][j];
        }
    }
}

// standalone gemm (both paths)
__global__ __launch_bounds__(256) void gemm_t_kernel(
    const float* __restrict__ x, const float* __restrict__ W12t,
    float* __restrict__ T)
{
    __shared__ float xs[256 * 32];
    __shared__ float wt[N_CLASS * 260];
    gemm_body(blockIdx.x, threadIdx.x, x, W12t, T, xs, wt);
}

// ---------------------------------------------------------------------------
// standalone fill: one edge per thread, NO LDS -> ~8 blocks/CU (32 waves/CU)
// vs 2 blocks/CU when fused with the 74.75KB-LDS gemm. The scatter is a
// latency chain (load -> atomic(returning) -> dependent store); 4x the
// resident waves = 4x the chains in flight. esrc/ew loaded before the
// atomic so they overlap the atomic's latency.
// ---------------------------------------------------------------------------
__global__ __launch_bounds__(256) void fill_slots_kernel(
    const int* __restrict__ esrc, const int* __restrict__ edst,
    const float* __restrict__ ew, int* __restrict__ cnt,
    int2* __restrict__ slots)
{
    int e = blockIdx.x * 256 + threadIdx.x;
    if (e >= N_EDGES) return;
    int   d = edst[e];
    int   s = esrc[e];
    float w = ew[e];
    int slot = atomicAdd(&cnt[d], 1);
    if (slot < SLOT_MAX)
        slots[(size_t)d * SLOT_MAX + slot] = make_int2(s, __float_as_int(w));
}

// ---------------------------------------------------------------------------
// CSR fallback: hist + 3-phase scan + fill
// ---------------------------------------------------------------------------
__global__ __launch_bounds__(256) void hist_kernel(
    const int* __restrict__ edst, int* __restrict__ cnt)
{
    int e = blockIdx.x * 256 + threadIdx.x;
    if (e >= N_EDGES) return;
    atomicAdd(&cnt[edst[e]], 1);
}

__global__ __launch_bounds__(256) void scan_partial_kernel(
    const int* __restrict__ cnt, int* __restrict__ bsum)
{
    __shared__ int red[256];
    int t = threadIdx.x;
    int idx = blockIdx.x * SCAN_CHUNK + t;
    int v = (idx < N_NODES) ? cnt[idx] : 0;
    red[t] = v;
    __syncthreads();
#pragma unroll
    for (int off = 128; off > 0; off >>= 1) {
        if (t < off) red[t] += red[t + off];
        __syncthreads();
    }
    if (t == 0) bsum[blockIdx.x] = red[0];
}

__global__ __launch_bounds__(512) void scan_block_kernel(
    const int* __restrict__ bsum, int* __restrict__ boff)
{
    __shared__ int s[512];
    int t = threadIdx.x;
    int v = (t < SCAN_NB) ? bsum[t] : 0;
    s[t] = v;
    __syncthreads();
#pragma unroll
    for (int off = 1; off < 512; off <<= 1) {
        int u = (t >= off) ? s[t - off] : 0;
        __syncthreads();
        s[t] += u;
        __syncthreads();
    }
    if (t < SCAN_NB) boff[t] = s[t] - v;
}

__global__ __launch_bounds__(256) void scan_final_kernel(
    const int* __restrict__ cnt, const int* __restrict__ boff,
    int* __restrict__ row_ptr)
{
    __shared__ int s[256];
    int t = threadIdx.x;
    int idx = blockIdx.x * SCAN_CHUNK + t;
    int v = (idx < N_NODES) ? cnt[idx] : 0;
    s[t] = v;
    __syncthreads();
#pragma unroll
    for (int off = 1; off < 256; off <<= 1) {
        int u = (t >= off) ? s[t - off] : 0;
        __syncthreads();
        s[t] += u;
        __syncthreads();
    }
    if (idx < N_NODES) row_ptr[idx] = boff[blockIdx.x] + s[t] - v;
}

__global__ __launch_bounds__(256) void fill_kernel(
    const int* __restrict__ esrc, const int* __restrict__ edst,
    const float* __restrict__ ew, int* __restrict__ row_ptr,
    int2* __restrict__ edges_s)
{
    int e = blockIdx.x * 256 + threadIdx.x;
    if (e >= N_EDGES) return;
    int d = edst[e];
    int pos = atomicAdd(&row_ptr[d], 1);
    edges_s[pos] = make_int2(esrc[e], __float_as_int(ew[e]));
}

// ---------------------------------------------------------------------------
// agg: Tout[d,:] = sum_e w_e * Tin[src_e,:].  10 lanes x float4 per node,
// 25 nodes / 256-block. 8-wide edge unroll: 8 independent gather chains
// in flight per lane.
// SMAX: fused bias + deg_w*c1 + log_softmax epilogue.
// ---------------------------------------------------------------------------
template<bool SLOTS, bool SMAX>
__global__ __launch_bounds__(256) void agg_kernel(
    const int2* __restrict__ edges_s, const int* __restrict__ meta,
    const float* __restrict__ Tin, float* __restrict__ Tout,
    const float* __restrict__ c1, const float* __restrict__ b2)
{
    __shared__ float red[25][11];
    __shared__ float wsh[25];
    const int t = threadIdx.x;
    const int nl  = t / 10;                 // 0..25 (idle if >=25)
    const int sub = t % 10;
    const int node = blockIdx.x * 25 + nl;
    const bool active = (t < 250) && (node < N_NODES);

    int beg = 0, end = 0;
    if (active) {
        if (SLOTS) {
            beg = node * SLOT_MAX;
            int c = meta[node];
            end = beg + (c > SLOT_MAX ? SLOT_MAX : c);
        } else {
            beg = node ? meta[node - 1] : 0;
            end = meta[node];
        }
    }

    const float4* Tin4 = (const float4*)Tin;
    float4 acc = make_float4(0.f, 0.f, 0.f, 0.f);
    float wsum = 0.f;

    int e = beg;
    for (; e + 7 < end; e += 8) {
        int2 a[8];
        float4 v[8];
#pragma unroll
        for (int q = 0; q < 8; ++q) a[q] = edges_s[e + q];
#pragma unroll
        for (int q = 0; q < 8; ++q) v[q] = Tin4[a[q].x * 10 + sub];
#pragma unroll
        for (int q = 0; q < 8; ++q) {
            float w = __int_as_float(a[q].y);
            acc.x = fmaf(w, v[q].x, acc.x);
            acc.y = fmaf(w, v[q].y, acc.y);
            acc.z = fmaf(w, v[q].z, acc.z);
            acc.w = fmaf(w, v[q].w, acc.w);
            if (SMAX) wsum += w;
        }
    }
    for (; e + 3 < end; e += 4) {
        int2 a[4];
        float4 v[4];
#pragma unroll
        for (int q = 0; q < 4; ++q) a[q] = edges_s[e + q];
#pragma unroll
        for (int q = 0; q < 4; ++q) v[q] = Tin4[a[q].x * 10 + sub];
#pragma unroll
        for (int q = 0; q < 4; ++q) {
            float w = __int_as_float(a[q].y);
            acc.x = fmaf(w, v[q].x, acc.x);
            acc.y = fmaf(w, v[q].y, acc.y);
            acc.z = fmaf(w, v[q].z, acc.z);
            acc.w = fmaf(w, v[q].w, acc.w);
            if (SMAX) wsum += w;
        }
    }
    for (; e < end; ++e) {
        int2 a0 = edges_s[e];
        float w0 = __int_as_float(a0.y);
        float4 v0 = Tin4[a0.x * 10 + sub];
        acc.x = fmaf(w0, v0.x, acc.x);
        acc.y = fmaf(w0, v0.y, acc.y);
        acc.z = fmaf(w0, v0.z, acc.z);
        acc.w = fmaf(w0, v0.w, acc.w);
        if (SMAX) wsum += w0;
    }

    if (!SMAX) {
        if (active) ((float4*)Tout)[(size_t)node * 10 + sub] = acc;
        return;
    }

    // ---- fused bias + log_softmax epilogue (all 256 threads hit syncs) ----
    if (active && sub == 0) wsh[nl] = wsum;
    __syncthreads();
    float dw = active ? wsh[nl] : 0.f;

    float4 cv = ((const float4*)c1)[sub];
    float4 bv = ((const float4*)b2)[sub];
    float4 z;
    z.x = fmaf(dw, cv.x, acc.x + bv.x);
    z.y = fmaf(dw, cv.y, acc.y + bv.y);
    z.z = fmaf(dw, cv.z, acc.z + bv.z);
    z.w = fmaf(dw, cv.w, acc.w + bv.w);

    float m4 = fmaxf(fmaxf(z.x, z.y), fmaxf(z.z, z.w));
    if (active) red[nl][sub] = m4;
    __syncthreads();
    float m = -INFINITY;
    if (active)
#pragma unroll
        for (int j = 0; j < 10; ++j) m = fmaxf(m, red[nl][j]);
    __syncthreads();

    float s4 = expf(z.x - m) + expf(z.y - m) + expf(z.z - m) + expf(z.w - m);
    if (active) red[nl][sub] = s4;
    __syncthreads();
    if (active) {
        float s = 0.f;
#pragma unroll
        for (int j = 0; j < 10; ++j) s += red[nl][j];
        float ls = m + logf(s);
        float4 o;
        o.x = z.x - ls; o.y = z.y - ls; o.z = z.z - ls; o.w = z.w - ls;
        ((float4*)Tout)[(size_t)node * 10 + sub] = o;
    }
}

// ---------------------------------------------------------------------------
extern "C" void kernel_launch(void* const* d_in, const int* in_sizes, int n_in,
                              void* d_out, int out_size, void* d_ws, size_t ws_size,
                              hipStream_t stream)
{
    const float* x    = (const float*)d_in[0];
    const int*   esrc = (const int*)  d_in[1];
    const int*   edst = (const int*)  d_in[2];
    const float* ew   = (const float*)d_in[3];
    const float* W1   = (const float*)d_in[4];
    const float* b1   = (const float*)d_in[5];
    const float* W2   = (const float*)d_in[6];
    const float* b2   = (const float*)d_in[7];
    float* out = (float*)d_out;

    char* ws = (char*)d_ws;
    const size_t SLOTS_BYTES = (size_t)N_NODES * SLOT_MAX * 8;     // 38.4 MB
    const size_t NEED_SLOTS  = SLOTS_BYTES + 32000000 + 1000000;   // ~71.4 MB
    const bool use_slots = (ws_size >= NEED_SLOTS);

    if (use_slots) {
        int2*  slots = (int2*) (ws);
        float* T     = (float*)(ws + SLOTS_BYTES);                  // 16 MB
        float* Y1    = (float*)(ws + SLOTS_BYTES + 16000000);       // 16 MB
        int*   cnt   = (int*)  (ws + SLOTS_BYTES + 32000000);       // 400 KB
        float* W12t  = (float*)(ws + SLOTS_BYTES + 32400000);       // 40 KB
        float* c1    = (float*)(ws + SLOTS_BYTES + 32441984);

        hipMemsetAsync(cnt, 0, 400000, stream);
        prep_kernel<<<(D_IN * N_CLASS + 255) / 256, 256, 0, stream>>>(W1, W2, b1, W12t, c1);
        fill_slots_kernel<<<EDGE_NB, 256, 0, stream>>>(esrc, edst, ew, cnt, slots);
        gemm_t_kernel<<<GEMM_NB, 256, 0, stream>>>(x, W12t, T);
        agg_kernel<true, false><<<(N_NODES + 24) / 25, 256, 0, stream>>>(
            slots, cnt, T, Y1, nullptr, nullptr);
        agg_kernel<true, true><<<(N_NODES + 24) / 25, 256, 0, stream>>>(
            slots, cnt, Y1, out, c1, b2);
    } else {
        float* T       = (float*)(ws);                         // 16 MB
        float* Y1      = (float*)(ws + 16000000);              // 16 MB
        int2*  edges_s = (int2*) (ws + 32000000);              // 12.8 MB
        int*   row_ptr = (int*)  (ws + 44800000);              // 400 KB
        int*   cnt     = (int*)  (ws + 45200016);              // 400 KB
        float* W12t    = (float*)(ws + 45600016);              // 40 KB
        float* c1      = (float*)(ws + 45640976);
        int*   bsum    = (int*)  (ws + 45641200);
        int*   boff    = (int*)  (ws + 45642800);

        hipMemsetAsync(cnt, 0, 400000, stream);
        prep_kernel<<<(D_IN * N_CLASS + 255) / 256, 256, 0, stream>>>(W1, W2, b1, W12t, c1);
        gemm_t_kernel<<<GEMM_NB, 256, 0, stream>>>(x, W12t, T);
        hist_kernel<<<EDGE_NB, 256, 0, stream>>>(edst, cnt);
        scan_partial_kernel<<<SCAN_NB, 256, 0, stream>>>(cnt, bsum);
        scan_block_kernel<<<1, 512, 0, stream>>>(bsum, boff);
        scan_final_kernel<<<SCAN_NB, 256, 0, stream>>>(cnt, boff, row_ptr);
        fill_kernel<<<EDGE_NB, 256, 0, stream>>>(esrc, edst, ew, row_ptr, edges_s);
        agg_kernel<false, false><<<(N_NODES + 24) / 25, 256, 0, stream>>>(
            edges_s, row_ptr, T, Y1, nullptr, nullptr);
        agg_kernel<false, true><<<(N_NODES + 24) / 25, 256, 0, stream>>>(
            edges_s, row_ptr, Y1, out, c1, b2);
    }
}

// Round 7
// 342.525 us; speedup vs baseline: 1.2712x; 1.2091x over previous
//
#include <hip/hip_runtime.h>
#include <hip/hip_fp16.h>
#include <math.h>

#define N_NODES 100000
#define N_EDGES 1600000
#define D_IN    256
#define D_HID   64
#define N_CLASS 40

#define SCAN_CHUNK 256
#define SCAN_NB    ((N_NODES + SCAN_CHUNK - 1) / SCAN_CHUNK)   // 391
#define SLOT_MAX   48     // Binomial(1.6M,1e-5): mean 16, P(deg>48) ~ 1e-10
#define GEMM_NB    ((N_NODES + 255) / 256)                     // 391
#define FILL_NB    ((N_EDGES + 255) / 256)                     // 6250
#define TSTRIDE    64     // half-elements per T/Y1 row (80B payload in 128B slot)

// ---------------------------------------------------------------------------
// prep: W12t[c][k] = sum_j W1[k][j]*W2[j][c]  (transposed 40x256),
//       c1[c] = sum_j b1[j]*W2[j][c]
// ---------------------------------------------------------------------------
__global__ __launch_bounds__(256) void prep_kernel(
    const float* __restrict__ W1, const float* __restrict__ W2,
    const float* __restrict__ b1, float* __restrict__ W12t, float* __restrict__ c1)
{
    int idx = blockIdx.x * 256 + threadIdx.x;
    if (idx < D_IN * N_CLASS) {
        int k = idx / N_CLASS;
        int c = idx - k * N_CLASS;
        float s = 0.f;
#pragma unroll
        for (int j = 0; j < D_HID; ++j)
            s = fmaf(W1[k * D_HID + j], W2[j * N_CLASS + c], s);
        W12t[c * D_IN + k] = s;
    }
    if (blockIdx.x == 0 && threadIdx.x < N_CLASS) {
        int c = threadIdx.x;
        float s = 0.f;
#pragma unroll
        for (int j = 0; j < D_HID; ++j)
            s = fmaf(b1[j], W2[j * N_CLASS + c], s);
        c1[c] = s;
    }
}

// ---------------------------------------------------------------------------
// gemm body (round-0 v3, verified): 256 rows x 40 cols per block, both
// operands in LDS, XOR-swizzled X tile, thread = 4 rows x 10 cols.
// 0 bank conflicts (measured). Output fp16 (TSTRIDE-half rows, 128B
// aligned) to cut downstream gather line-traffic 192B->128B per edge.
// ---------------------------------------------------------------------------
__device__ __forceinline__ void gemm_body(
    int gblk, int tid,
    const float* __restrict__ x, const float* __restrict__ W12t,
    __half* __restrict__ T, float* xs, float* wt)
{
    const int row0 = gblk * 256;

    for (int i = tid; i < N_CLASS * D_IN; i += 256) {
        int c = i >> 8;
        int k = i & 255;
        wt[c * 260 + k] = W12t[i];
    }

    const int rg = tid >> 2;       // 0..63  (4 rows each)
    const int cg = tid & 3;        // 0..3   (10 cols each)
    const int c0 = cg * 10;        // even -> __half2-aligned

    float acc[4][10];
#pragma unroll
    for (int r = 0; r < 4; ++r)
#pragma unroll
        for (int j = 0; j < 10; ++j) acc[r][j] = 0.f;

    const float4* x4 = (const float4*)x;
    float4* xs4 = (float4*)xs;
    const float4* wt4 = (const float4*)wt;

    for (int kb = 0; kb < 8; ++kb) {
        __syncthreads();
#pragma unroll
        for (int ph = 0; ph < 8; ++ph) {
            int i = ph * 256 + tid;
            int r  = i >> 3;
            int c4 = i & 7;
            int grow = min(row0 + r, N_NODES - 1);
            float4 v = x4[(size_t)grow * 64 + kb * 8 + c4];
            xs4[r * 8 + (c4 ^ ((r >> 2) & 7))] = v;
        }
        __syncthreads();

#pragma unroll
        for (int k4 = 0; k4 < 8; ++k4) {
            float4 xv[4];
#pragma unroll
            for (int r = 0; r < 4; ++r)
                xv[r] = xs4[(rg * 4 + r) * 8 + (k4 ^ (rg & 7))];
#pragma unroll
            for (int j = 0; j < 10; ++j) {
                float4 w = wt4[(c0 + j) * 65 + kb * 8 + k4];
#pragma unroll
                for (int r = 0; r < 4; ++r)
                    acc[r][j] = fmaf(xv[r].x, w.x,
                                fmaf(xv[r].y, w.y,
                                fmaf(xv[r].z, w.z,
                                fmaf(xv[r].w, w.w, acc[r][j]))));
            }
        }
    }

#pragma unroll
    for (int r = 0; r < 4; ++r) {
        int row = row0 + rg * 4 + r;
        if (row < N_NODES) {
            __half2* Trow = (__half2*)(T + (size_t)row * TSTRIDE + c0);
#pragma unroll
            for (int q = 0; q < 5; ++q)
                Trow[q] = __floats2half2_rn(acc[r][2 * q], acc[r][2 * q + 1]);
        }
    }
}

// ---------------------------------------------------------------------------
// fused gemm + fill_slots (R0 structure, measured 140us): blocks [0,GEMM_NB)
// do the dense transform, blocks [GEMM_NB,GEMM_NB+FILL_NB) bin one edge per
// thread. R4 proved the fill is memory-system-throughput-bound (72% occ ==
// 20% occ in time), so the 74.75KB LDS tax on fill blocks costs nothing and
// the fusion buys gemm/fill overlap on the serial stream.
// ---------------------------------------------------------------------------
__global__ __launch_bounds__(256) void gemm_fill_kernel(
    const float* __restrict__ x, const float* __restrict__ W12t,
    __half* __restrict__ T,
    const int* __restrict__ esrc, const int* __restrict__ edst,
    const float* __restrict__ ew, int* __restrict__ cnt,
    int2* __restrict__ slots)
{
    __shared__ float xs[256 * 32];      // 32 KB
    __shared__ float wt[N_CLASS * 260]; // 41.6 KB  (74.4 KB -> 2 blocks/CU)
    const int tid = threadIdx.x;

    if (blockIdx.x < GEMM_NB) {
        gemm_body(blockIdx.x, tid, x, W12t, T, xs, wt);
    } else {
        int e = (blockIdx.x - GEMM_NB) * 256 + tid;
        if (e < N_EDGES) {
            int   d = edst[e];
            int   s = esrc[e];
            float w = ew[e];
            int slot = atomicAdd(&cnt[d], 1);
            if (slot < SLOT_MAX)
                slots[(size_t)d * SLOT_MAX + slot] =
                    make_int2(s, __float_as_int(w));
        }
    }
}

// standalone gemm (CSR fallback path)
__global__ __launch_bounds__(256) void gemm_t_kernel(
    const float* __restrict__ x, const float* __restrict__ W12t,
    __half* __restrict__ T)
{
    __shared__ float xs[256 * 32];
    __shared__ float wt[N_CLASS * 260];
    gemm_body(blockIdx.x, threadIdx.x, x, W12t, T, xs, wt);
}

// ---------------------------------------------------------------------------
// CSR fallback: hist + 3-phase scan + fill
// ---------------------------------------------------------------------------
__global__ __launch_bounds__(256) void hist_kernel(
    const int* __restrict__ edst, int* __restrict__ cnt)
{
    int e = blockIdx.x * 256 + threadIdx.x;
    if (e >= N_EDGES) return;
    atomicAdd(&cnt[edst[e]], 1);
}

__global__ __launch_bounds__(256) void scan_partial_kernel(
    const int* __restrict__ cnt, int* __restrict__ bsum)
{
    __shared__ int red[256];
    int t = threadIdx.x;
    int idx = blockIdx.x * SCAN_CHUNK + t;
    int v = (idx < N_NODES) ? cnt[idx] : 0;
    red[t] = v;
    __syncthreads();
#pragma unroll
    for (int off = 128; off > 0; off >>= 1) {
        if (t < off) red[t] += red[t + off];
        __syncthreads();
    }
    if (t == 0) bsum[blockIdx.x] = red[0];
}

__global__ __launch_bounds__(512) void scan_block_kernel(
    const int* __restrict__ bsum, int* __restrict__ boff)
{
    __shared__ int s[512];
    int t = threadIdx.x;
    int v = (t < SCAN_NB) ? bsum[t] : 0;
    s[t] = v;
    __syncthreads();
#pragma unroll
    for (int off = 1; off < 512; off <<= 1) {
        int u = (t >= off) ? s[t - off] : 0;
        __syncthreads();
        s[t] += u;
        __syncthreads();
    }
    if (t < SCAN_NB) boff[t] = s[t] - v;
}

__global__ __launch_bounds__(256) void scan_final_kernel(
    const int* __restrict__ cnt, const int* __restrict__ boff,
    int* __restrict__ row_ptr)
{
    __shared__ int s[256];
    int t = threadIdx.x;
    int idx = blockIdx.x * SCAN_CHUNK + t;
    int v = (idx < N_NODES) ? cnt[idx] : 0;
    s[t] = v;
    __syncthreads();
#pragma unroll
    for (int off = 1; off < 256; off <<= 1) {
        int u = (t >= off) ? s[t - off] : 0;
        __syncthreads();
        s[t] += u;
        __syncthreads();
    }
    if (idx < N_NODES) row_ptr[idx] = boff[blockIdx.x] + s[t] - v;
}

__global__ __launch_bounds__(256) void fill_kernel(
    const int* __restrict__ esrc, const int* __restrict__ edst,
    const float* __restrict__ ew, int* __restrict__ row_ptr,
    int2* __restrict__ edges_s)
{
    int e = blockIdx.x * 256 + threadIdx.x;
    if (e >= N_EDGES) return;
    int d = edst[e];
    int pos = atomicAdd(&row_ptr[d], 1);
    edges_s[pos] = make_int2(esrc[e], __float_as_int(ew[e]));
}

// ---------------------------------------------------------------------------
// agg: Tout[d,:] = sum_e w_e * Tin[src_e,:].  Tin is fp16, TSTRIDE-half rows
// (128B-aligned) -> each edge-gather touches exactly 2 cache lines (was 3
// with f32 rows). 10 lanes x 4-halves (uint2) per node, 25 nodes / block,
// 8-wide edge unroll for MLP.
// SMAX: fused bias + deg_w*c1 + log_softmax epilogue, f32 output.
// ---------------------------------------------------------------------------
template<bool SLOTS, bool SMAX>
__global__ __launch_bounds__(256) void agg_kernel(
    const int2* __restrict__ edges_s, const int* __restrict__ meta,
    const __half* __restrict__ Tin, void* __restrict__ Tout,
    const float* __restrict__ c1, const float* __restrict__ b2)
{
    __shared__ float red[25][11];
    __shared__ float wsh[25];
    const int t = threadIdx.x;
    const int nl  = t / 10;                 // 0..25 (idle if >=25)
    const int sub = t % 10;
    const int node = blockIdx.x * 25 + nl;
    const bool active = (t < 250) && (node < N_NODES);

    int beg = 0, end = 0;
    if (active) {
        if (SLOTS) {
            beg = node * SLOT_MAX;
            int c = meta[node];
            end = beg + (c > SLOT_MAX ? SLOT_MAX : c);
        } else {
            beg = node ? meta[node - 1] : 0;
            end = meta[node];
        }
    }

    const uint2* Tin8 = (const uint2*)Tin;   // 4 halves per uint2; row = 16 uint2
    float4 acc = make_float4(0.f, 0.f, 0.f, 0.f);
    float wsum = 0.f;

    int e = beg;
    for (; e + 7 < end; e += 8) {
        int2 a[8];
        uint2 g[8];
#pragma unroll
        for (int q = 0; q < 8; ++q) a[q] = edges_s[e + q];
#pragma unroll
        for (int q = 0; q < 8; ++q) g[q] = Tin8[a[q].x * 16 + sub];
#pragma unroll
        for (int q = 0; q < 8; ++q) {
            float w = __int_as_float(a[q].y);
            float2 f0 = __half22float2(*(const __half2*)&g[q].x);
            float2 f1 = __half22float2(*(const __half2*)&g[q].y);
            acc.x = fmaf(w, f0.x, acc.x);
            acc.y = fmaf(w, f0.y, acc.y);
            acc.z = fmaf(w, f1.x, acc.z);
            acc.w = fmaf(w, f1.y, acc.w);
            if (SMAX) wsum += w;
        }
    }
    for (; e < end; ++e) {
        int2 a0 = edges_s[e];
        float w0 = __int_as_float(a0.y);
        uint2 g0 = Tin8[a0.x * 16 + sub];
        float2 f0 = __half22float2(*(const __half2*)&g0.x);
        float2 f1 = __half22float2(*(const __half2*)&g0.y);
        acc.x = fmaf(w0, f0.x, acc.x);
        acc.y = fmaf(w0, f0.y, acc.y);
        acc.z = fmaf(w0, f1.x, acc.z);
        acc.w = fmaf(w0, f1.y, acc.w);
        if (SMAX) wsum += w0;
    }

    if (!SMAX) {
        if (active) {
            uint2 o;
            *(__half2*)&o.x = __floats2half2_rn(acc.x, acc.y);
            *(__half2*)&o.y = __floats2half2_rn(acc.z, acc.w);
            ((uint2*)Tout)[(size_t)node * 16 + sub] = o;
        }
        return;
    }

    // ---- fused bias + log_softmax epilogue (all 256 threads hit syncs) ----
    if (active && sub == 0) wsh[nl] = wsum;
    __syncthreads();
    float dw = active ? wsh[nl] : 0.f;

    float4 cv = ((const float4*)c1)[sub];
    float4 bv = ((const float4*)b2)[sub];
    float4 z;
    z.x = fmaf(dw, cv.x, acc.x + bv.x);
    z.y = fmaf(dw, cv.y, acc.y + bv.y);
    z.z = fmaf(dw, cv.z, acc.z + bv.z);
    z.w = fmaf(dw, cv.w, acc.w + bv.w);

    float m4 = fmaxf(fmaxf(z.x, z.y), fmaxf(z.z, z.w));
    if (active) red[nl][sub] = m4;
    __syncthreads();
    float m = -INFINITY;
    if (active)
#pragma unroll
        for (int j = 0; j < 10; ++j) m = fmaxf(m, red[nl][j]);
    __syncthreads();

    float s4 = expf(z.x - m) + expf(z.y - m) + expf(z.z - m) + expf(z.w - m);
    if (active) red[nl][sub] = s4;
    __syncthreads();
    if (active) {
        float s = 0.f;
#pragma unroll
        for (int j = 0; j < 10; ++j) s += red[nl][j];
        float ls = m + logf(s);
        float4 o;
        o.x = z.x - ls; o.y = z.y - ls; o.z = z.z - ls; o.w = z.w - ls;
        ((float4*)Tout)[(size_t)node * 10 + sub] = o;
    }
}

// ---------------------------------------------------------------------------
extern "C" void kernel_launch(void* const* d_in, const int* in_sizes, int n_in,
                              void* d_out, int out_size, void* d_ws, size_t ws_size,
                              hipStream_t stream)
{
    const float* x    = (const float*)d_in[0];
    const int*   esrc = (const int*)  d_in[1];
    const int*   edst = (const int*)  d_in[2];
    const float* ew   = (const float*)d_in[3];
    const float* W1   = (const float*)d_in[4];
    const float* b1   = (const float*)d_in[5];
    const float* W2   = (const float*)d_in[6];
    const float* b2   = (const float*)d_in[7];
    float* out = (float*)d_out;

    char* ws = (char*)d_ws;
    const size_t SLOTS_BYTES = (size_t)N_NODES * SLOT_MAX * 8;     // 38.4 MB
    const size_t NEED_SLOTS  = SLOTS_BYTES + 32000000 + 1000000;   // ~71.4 MB
    const bool use_slots = (ws_size >= NEED_SLOTS);

    if (use_slots) {
        int2*   slots = (int2*)  (ws);
        __half* T     = (__half*)(ws + SLOTS_BYTES);                  // 12.8 MB
        __half* Y1    = (__half*)(ws + SLOTS_BYTES + 16000000);       // 12.8 MB
        int*    cnt   = (int*)   (ws + SLOTS_BYTES + 32000000);       // 400 KB
        float*  W12t  = (float*) (ws + SLOTS_BYTES + 32400000);       // 40 KB
        float*  c1    = (float*) (ws + SLOTS_BYTES + 32441984);

        hipMemsetAsync(cnt, 0, 400000, stream);
        prep_kernel<<<(D_IN * N_CLASS + 255) / 256, 256, 0, stream>>>(W1, W2, b1, W12t, c1);
        gemm_fill_kernel<<<GEMM_NB + FILL_NB, 256, 0, stream>>>(
            x, W12t, T, esrc, edst, ew, cnt, slots);
        agg_kernel<true, false><<<(N_NODES + 24) / 25, 256, 0, stream>>>(
            slots, cnt, T, Y1, nullptr, nullptr);
        agg_kernel<true, true><<<(N_NODES + 24) / 25, 256, 0, stream>>>(
            slots, cnt, Y1, out, c1, b2);
    } else {
        __half* T       = (__half*)(ws);                         // 12.8 MB
        __half* Y1      = (__half*)(ws + 16000000);              // 12.8 MB
        int2*   edges_s = (int2*)  (ws + 32000000);              // 12.8 MB
        int*    row_ptr = (int*)   (ws + 44800000);              // 400 KB
        int*    cnt     = (int*)   (ws + 45200016);              // 400 KB
        float*  W12t    = (float*) (ws + 45600016);              // 40 KB
        float*  c1      = (float*) (ws + 45640976);
        int*    bsum    = (int*)   (ws + 45641200);
        int*    boff    = (int*)   (ws + 45642800);

        hipMemsetAsync(cnt, 0, 400000, stream);
        prep_kernel<<<(D_IN * N_CLASS + 255) / 256, 256, 0, stream>>>(W1, W2, b1, W12t, c1);
        gemm_t_kernel<<<GEMM_NB, 256, 0, stream>>>(x, W12t, T);
        hist_kernel<<<FILL_NB, 256, 0, stream>>>(edst, cnt);
        scan_partial_kernel<<<SCAN_NB, 256, 0, stream>>>(cnt, bsum);
        scan_block_kernel<<<1, 512, 0, stream>>>(bsum, boff);
        scan_final_kernel<<<SCAN_NB, 256, 0, stream>>>(cnt, boff, row_ptr);
        fill_kernel<<<FILL_NB, 256, 0, stream>>>(esrc, edst, ew, row_ptr, edges_s);
        agg_kernel<false, false><<<(N_NODES + 24) / 25, 256, 0, stream>>>(
            edges_s, row_ptr, T, Y1, nullptr, nullptr);
        agg_kernel<false, true><<<(N_NODES + 24) / 25, 256, 0, stream>>>(
            edges_s, row_ptr, Y1, out, c1, b2);
    }
}